// Round 3
// baseline (421.998 us; speedup 1.0000x reference)
//
#include <hip/hip_runtime.h>

#define S 512
#define B 1024
#define K 48
#define LN2 0.6931471805599453f
#define PF 8
#define NBLK 512   // 2 chains per wave: b and b+NBLK

__global__ void __launch_bounds__(64) zero_out(float* o) {
    if (threadIdx.x == 0) o[0] = 0.f;
}

// s_j = sum_k f[k] * eT[k]  (f broadcast identical across lanes, eT per-lane column j)
__device__ __forceinline__ float matvec48(const float4* f, const float* eT) {
    float s0 = 0.f, s1 = 0.f, s2 = 0.f, s3 = 0.f;
    #pragma unroll
    for (int i = 0; i < 12; ++i) {
        s0 = fmaf(f[i].x, eT[4 * i + 0], s0);
        s1 = fmaf(f[i].y, eT[4 * i + 1], s1);
        s2 = fmaf(f[i].z, eT[4 * i + 2], s2);
        s3 = fmaf(f[i].w, eT[4 * i + 3], s3);
    }
    return (s0 + s1) + (s2 + s3);
}

__global__ void __launch_bounds__(64) crf_kernel(
    const float* __restrict__ em, const int* __restrict__ tags,
    const int* __restrict__ mask, const float* __restrict__ trans,
    const float* __restrict__ start_tr, const float* __restrict__ end_tr,
    float* __restrict__ out)
{
    const int lane = threadIdx.x;
    const int b0   = blockIdx.x;
    const int b1   = blockIdx.x + NBLK;
    __shared__ __align__(16) float sh[2][K];

    // ---------------- score for both chains (lane-parallel over t) ----------------
    float scA = 0.f, scB = 0.f;
    int mcA = 0, mcB = 0;
    #pragma unroll
    for (int i = 0; i < S / 64; ++i) {
        int t = lane + 64 * i;
        {
            int tag = tags[t * B + b0];
            int mk  = mask[t * B + b0];
            mcA += mk;
            if (t == 0) scA += start_tr[tag] + em[(size_t)b0 * K + tag];
            else {
                int tagp = tags[(t - 1) * B + b0];
                float add = trans[tagp * K + tag] + em[((size_t)t * B + b0) * K + tag];
                scA += mk ? add : 0.f;
            }
        }
        {
            int tag = tags[t * B + b1];
            int mk  = mask[t * B + b1];
            mcB += mk;
            if (t == 0) scB += start_tr[tag] + em[(size_t)b1 * K + tag];
            else {
                int tagp = tags[(t - 1) * B + b1];
                float add = trans[tagp * K + tag] + em[((size_t)t * B + b1) * K + tag];
                scB += mk ? add : 0.f;
            }
        }
    }
    #pragma unroll
    for (int off = 32; off > 0; off >>= 1) {
        scA += __shfl_xor(scA, off);
        scB += __shfl_xor(scB, off);
        mcA += __shfl_xor(mcA, off);
        mcB += __shfl_xor(mcB, off);
    }
    int lA = mcA - 1; if (lA < 0) lA += S;
    int lB = mcB - 1; if (lB < 0) lB += S;
    scA += end_tr[tags[lA * B + b0]];
    scB += end_tr[tags[lB * B + b1]];

    // ---------------- partition: linear-space forward, 2 chains ILP ----------------
    const int  j      = (lane < K) ? lane : 0;
    const bool active = lane < K;

    float eT[K];                       // column j of exp(T), shared by both chains
    #pragma unroll
    for (int k = 0; k < K; ++k) eT[k] = __expf(trans[k * K + j]);

    float aA = __expf(start_tr[j] + em[(size_t)b0 * K + j]);
    float aB = __expf(start_tr[j] + em[(size_t)b1 * K + j]);
    int   offA = 0, offB = 0;
    float sclA = 1.f, sclB = 1.f;

    if (active) { sh[0][j] = aA; sh[1][j] = aB; }
    const float4* shA = (const float4*)sh[0];
    const float4* shB = (const float4*)sh[1];

    float emA[PF], emB[PF];
    int   mkA[PF], mkB[PF];
    #pragma unroll
    for (int i = 0; i < PF; ++i) {
        emA[i] = em[((size_t)(1 + i) * B + b0) * K + j];
        emB[i] = em[((size_t)(1 + i) * B + b1) * K + j];
        mkA[i] = mask[(size_t)(1 + i) * B + b0];
        mkB[i] = mask[(size_t)(1 + i) * B + b1];
    }
    float eexpA = __expf(emA[0]);
    float eexpB = __expf(emB[0]);

#define STEP2(u_, t_, PFON_)                                                    \
    do {                                                                        \
        float4 fA_[12], fB_[12];                                                \
        _Pragma("unroll") for (int i_ = 0; i_ < 12; ++i_) fA_[i_] = shA[i_];    \
        _Pragma("unroll") for (int i_ = 0; i_ < 12; ++i_) fB_[i_] = shB[i_];    \
        float sA_ = matvec48(fA_, eT);                                          \
        float sB_ = matvec48(fB_, eT);                                          \
        float anA_ = sA_ * eexpA;                                               \
        float anB_ = sB_ * eexpB;                                               \
        aA = mkA[u_] ? anA_ : aA;  aA *= sclA;                                  \
        aB = mkB[u_] ? anB_ : aB;  aB *= sclB;                                  \
        if (lane < K) { sh[0][lane] = aA; sh[1][lane] = aB; }                   \
        eexpA = __expf(emA[((u_) + 1) & 7]);                                    \
        eexpB = __expf(emB[((u_) + 1) & 7]);                                    \
        if (PFON_) {                                                            \
            int tp_ = (t_) + PF;                                                \
            if (tp_ < S) {                                                      \
                emA[u_] = em[((size_t)tp_ * B + b0) * K + j];                   \
                emB[u_] = em[((size_t)tp_ * B + b1) * K + j];                   \
                mkA[u_] = mask[(size_t)tp_ * B + b0];                           \
                mkB[u_] = mask[(size_t)tp_ * B + b1];                           \
            }                                                                   \
        }                                                                       \
        if (((u_) & 7) == 7) {   /* renorm every 8 steps, SALU bookkeeping */   \
            int bA_ = __builtin_amdgcn_readlane(__float_as_int(aA), 0);         \
            int bB_ = __builtin_amdgcn_readlane(__float_as_int(aB), 0);         \
            int EA_ = ((bA_ >> 23) & 255) - 127;                                \
            int EB_ = ((bB_ >> 23) & 255) - 127;                                \
            offA += EA_;  sclA = __int_as_float((127 - EA_) << 23);             \
            offB += EB_;  sclB = __int_as_float((127 - EB_) << 23);             \
        } else { sclA = 1.f; sclB = 1.f; }                                      \
    } while (0)

    // main: t = 1 .. 504
    for (int t0 = 1; t0 <= S - 2 * PF + 1; t0 += PF) {
        #pragma unroll
        for (int u = 0; u < PF; ++u) STEP2(u, t0 + u, true);
    }
    // tail: t = 505 .. 511
    #pragma unroll
    for (int u = 0; u < PF - 1; ++u) STEP2(u, (S - PF + 1) + u, false);
#undef STEP2

    float vA = active ? aA * __expf(end_tr[j]) : 0.f;
    float vB = active ? aB * __expf(end_tr[j]) : 0.f;
    #pragma unroll
    for (int off = 32; off > 0; off >>= 1) {
        vA += __shfl_xor(vA, off);
        vB += __shfl_xor(vB, off);
    }
    float pA = (float)offA * LN2 + __logf(vA);
    float pB = (float)offB * LN2 + __logf(vB);

    if (lane == 0) atomicAdd(out, (pA - scA) + (pB - scB));
}

extern "C" void kernel_launch(void* const* d_in, const int* in_sizes, int n_in,
                              void* d_out, int out_size, void* d_ws, size_t ws_size,
                              hipStream_t stream) {
    const float* em       = (const float*)d_in[0];
    const int*   tags     = (const int*)d_in[1];
    const int*   mask     = (const int*)d_in[2];
    const float* trans    = (const float*)d_in[3];
    const float* start_tr = (const float*)d_in[4];
    const float* end_tr   = (const float*)d_in[5];
    float* out = (float*)d_out;

    zero_out<<<dim3(1), dim3(64), 0, stream>>>(out);
    crf_kernel<<<dim3(NBLK), dim3(64), 0, stream>>>(em, tags, mask, trans,
                                                    start_tr, end_tr, out);
}

// Round 6
// 365.353 us; speedup vs baseline: 1.1550x; 1.1550x over previous
//
#include <hip/hip_runtime.h>

#define S 512
#define B 1024
#define K 48
#define NCH 16            // chains per block = MFMA N
#define NBLK (B / NCH)    // 64 blocks
#define PF 8
#define LN2 0.6931471805599453f
#define LOG2E 1.4426950408889634f

typedef float f4 __attribute__((ext_vector_type(4)));
typedef __bf16 b8 __attribute__((ext_vector_type(8)));
union BU { b8 v; unsigned u[4]; };

__device__ __forceinline__ f4 mfma32(b8 a, b8 b, f4 c) {
    return __builtin_amdgcn_mfma_f32_16x16x32_bf16(a, b, c, 0, 0, 0);
}

__global__ void __launch_bounds__(64) zero_out(float* o) {
    if (threadIdx.x == 0) o[0] = 0.f;
}

__global__ void __launch_bounds__(64, 1) crf_kernel(
    const float* __restrict__ em, const int* __restrict__ tags,
    const int* __restrict__ mask, const float* __restrict__ trans,
    const float* __restrict__ start_tr, const float* __restrict__ end_tr,
    float* __restrict__ out)
{
    const int lane = threadIdx.x;
    const int c    = lane & 15;     // chain within block / MFMA column
    const int g    = lane >> 4;     // 4-row group
    const int bb   = blockIdx.x * NCH;
    const int b    = bb + c;

    // ---------------- score: lane = (chain c, t-quarter g) ----------------
    float sc = 0.f;
    int   mc = 0;
    {
        int tagp = 0;
        if (g > 0) tagp = tags[(128 * g - 1) * B + b];
        #pragma unroll 4
        for (int i = 0; i < 128; ++i) {
            int t   = 128 * g + i;
            int tag = tags[t * B + b];
            int mk  = mask[t * B + b];
            mc += mk;
            if (t == 0) {
                sc += start_tr[tag] + em[(size_t)b * K + tag];
            } else {
                float add = trans[tagp * K + tag] + em[((size_t)t * B + b) * K + tag];
                sc += mk ? add : 0.f;
            }
            tagp = tag;
        }
        sc += __shfl_xor(sc, 16);  sc += __shfl_xor(sc, 32);
        mc += __shfl_xor(mc, 16);  mc += __shfl_xor(mc, 32);
        int lt = mc - 1; if (lt < 0) lt += S;
        sc += end_tr[tags[lt * B + b]];        // replicated over g
    }

    // ---------------- partition: MFMA forward algorithm ----------------
    // A[row=16tr+c][k] = exp(trans[k][16tr+c]), padded 0 for k>=48
    // operand k-map: k = 32*kc + 16*(e>>2) + 4*g + (e&3)
    BU Afr[3][2];
    #pragma unroll
    for (int tr = 0; tr < 3; ++tr)
        #pragma unroll
        for (int kc = 0; kc < 2; ++kc)
            #pragma unroll
            for (int e = 0; e < 8; ++e) {
                int kk = 32 * kc + 16 * (e >> 2) + 4 * g + (e & 3);
                float v = (kk < K) ? __expf(trans[kk * K + 16 * tr + c]) : 0.f;
                Afr[tr][kc].v[e] = (__bf16)v;
            }

    // B init: alpha0[k] = exp(start[k] + em[0][b][k])
    BU Bf[2];
    #pragma unroll
    for (int kc = 0; kc < 2; ++kc)
        #pragma unroll
        for (int e = 0; e < 8; ++e) {
            int kk = 32 * kc + 16 * (e >> 2) + 4 * g + (e & 3);
            float v = (kk < K) ? __expf(start_tr[kk] + em[(size_t)b * K + kk]) : 1.f;
            Bf[kc].v[e] = (__bf16)v;
        }

    // prefetch ring: em rows for C-layout (rows 16tr+4g..+3), mask per (t,chain)
    f4  emr[PF][3];
    int mkr[PF];
    #pragma unroll
    for (int i = 0; i < PF; ++i) {
        const float* rp = em + ((size_t)(1 + i) * B + b) * K + 4 * g;
        emr[i][0] = *(const f4*)(rp);
        emr[i][1] = *(const f4*)(rp + 16);
        emr[i][2] = *(const f4*)(rp + 32);
        mkr[i]    = mask[(1 + i) * B + b];
    }
    f4 eem[3];
    #pragma unroll
    for (int tr = 0; tr < 3; ++tr)
        #pragma unroll
        for (int e = 0; e < 4; ++e)
            eem[tr][e] = exp2f(emr[0][tr][e] * LOG2E);

    int offc  = 0;   // per-chain log2 offset (replicated over g)
    int n_cur = 0;   // pending renorm amount for the keep-old path

#define STEP(u_)                                                                \
    {                                                                           \
        f4 c0 = {0.f,0.f,0.f,0.f}, c1 = {0.f,0.f,0.f,0.f},                      \
           c2 = {0.f,0.f,0.f,0.f};                                              \
        c0 = mfma32(Afr[0][0].v, Bf[0].v, c0);                                  \
        c1 = mfma32(Afr[1][0].v, Bf[0].v, c1);                                  \
        c2 = mfma32(Afr[2][0].v, Bf[0].v, c2);                                  \
        c0 = mfma32(Afr[0][1].v, Bf[1].v, c0);                                  \
        c1 = mfma32(Afr[1][1].v, Bf[1].v, c1);                                  \
        c2 = mfma32(Afr[2][1].v, Bf[1].v, c2);                                  \
        c0 *= eem[0]; c1 *= eem[1]; c2 *= eem[2];                               \
        bool keep = mkr[u_] != 0;                                               \
        unsigned adj = (unsigned)(n_cur * 0x00800080);   /* bf16 exp-field */   \
        n_cur = 0;                                                              \
        BU nb0, nb1;                                                            \
        nb0.v[0] = (__bf16)c0[0]; nb0.v[1] = (__bf16)c0[1];                     \
        nb0.v[2] = (__bf16)c0[2]; nb0.v[3] = (__bf16)c0[3];                     \
        nb0.v[4] = (__bf16)c1[0]; nb0.v[5] = (__bf16)c1[1];                     \
        nb0.v[6] = (__bf16)c1[2]; nb0.v[7] = (__bf16)c1[3];                     \
        nb1.v[0] = (__bf16)c2[0]; nb1.v[1] = (__bf16)c2[1];                     \
        nb1.v[2] = (__bf16)c2[2]; nb1.v[3] = (__bf16)c2[3];                     \
        nb1.v[4] = nb1.v[0]; nb1.v[5] = nb1.v[1];                               \
        nb1.v[6] = nb1.v[2]; nb1.v[7] = nb1.v[3];   /* pad rows, A=0 there */   \
        _Pragma("unroll")                                                       \
        for (int w = 0; w < 4; ++w) {                                           \
            Bf[0].u[w] = keep ? nb0.u[w] : (Bf[0].u[w] - adj);                  \
            Bf[1].u[w] = keep ? nb1.u[w] : (Bf[1].u[w] - adj);                  \
        }                                                                       \
        const int tp = t0 + (u_) + PF;                                          \
        if (tp < S) {                                                           \
            const float* rp = em + ((size_t)tp * B + b) * K + 4 * g;            \
            emr[u_][0] = *(const f4*)(rp);                                      \
            emr[u_][1] = *(const f4*)(rp + 16);                                 \
            emr[u_][2] = *(const f4*)(rp + 32);                                 \
            mkr[u_]    = mask[tp * B + b];                                      \
        }                                                                       \
        float nrmf = 0.f;                                                       \
        if ((u_) == 7) {   /* per-chain renorm, applied next step */            \
            float rv = __shfl((float)Bf[0].v[0], c);   /* chain c row 0 */      \
            int   E  = ((__float_as_int(rv) >> 23) & 255) - 127;                \
            int   n  = E + 30;             /* retarget alpha[0] to 2^-30 */     \
            offc += n;  n_cur = n;  nrmf = -(float)n;                           \
        }                                                                       \
        const int sn = ((u_) + 1) & 7;                                          \
        _Pragma("unroll")                                                       \
        for (int tr_ = 0; tr_ < 3; ++tr_)                                       \
            _Pragma("unroll")                                                   \
            for (int e_ = 0; e_ < 4; ++e_)                                      \
                eem[tr_][e_] = exp2f(fmaf(emr[sn][tr_][e_], LOG2E, nrmf));      \
    }

    // main blocks: t = 1 .. 504 (63 full blocks of 8)
    for (int t0 = 1; t0 + 7 < S; t0 += PF) {
        STEP(0) STEP(1) STEP(2) STEP(3) STEP(4) STEP(5) STEP(6) STEP(7)
    }
    // tail: t = 505 .. 511 (7 steps)
    {
        const int t0 = S - 7;
        STEP(0) STEP(1) STEP(2) STEP(3) STEP(4) STEP(5) STEP(6)
    }
#undef STEP

    // partition_c = offc*ln2 + ln( sum_k alpha[k][c] * exp(end[k]) )
    float val = 0.f;
    #pragma unroll
    for (int e = 0; e < 4; ++e) {
        val += (float)Bf[0].v[e]     * __expf(end_tr[4 * g + e]);
        val += (float)Bf[0].v[4 + e] * __expf(end_tr[16 + 4 * g + e]);
        val += (float)Bf[1].v[e]     * __expf(end_tr[32 + 4 * g + e]);
    }
    val += __shfl_xor(val, 16);
    val += __shfl_xor(val, 32);
    float part = (float)offc * LN2 + logf(val);

    // contrib replicated 4x over g -> sum all lanes, scale by 1/4
    float contrib = part - sc;
    #pragma unroll
    for (int off = 32; off > 0; off >>= 1) contrib += __shfl_xor(contrib, off);
    if (lane == 0) atomicAdd(out, contrib * 0.25f);
}

extern "C" void kernel_launch(void* const* d_in, const int* in_sizes, int n_in,
                              void* d_out, int out_size, void* d_ws, size_t ws_size,
                              hipStream_t stream) {
    const float* em       = (const float*)d_in[0];
    const int*   tags     = (const int*)d_in[1];
    const int*   mask     = (const int*)d_in[2];
    const float* trans    = (const float*)d_in[3];
    const float* start_tr = (const float*)d_in[4];
    const float* end_tr   = (const float*)d_in[5];
    float* out = (float*)d_out;

    zero_out<<<dim3(1), dim3(64), 0, stream>>>(out);
    crf_kernel<<<dim3(NBLK), dim3(64), 0, stream>>>(em, tags, mask, trans,
                                                    start_tr, end_tr, out);
}

// Round 7
// 354.816 us; speedup vs baseline: 1.1893x; 1.0297x over previous
//
#include <hip/hip_runtime.h>

#define S 512
#define B 1024
#define K 48
#define NCH 16            // chains per block = MFMA N
#define NBLK (B / NCH)    // 64 blocks
#define PF 8
#define LN2 0.6931471805599453f
#define LOG2E 1.4426950408889634f

typedef float f4 __attribute__((ext_vector_type(4)));
typedef __bf16 b8 __attribute__((ext_vector_type(8)));
union BU { b8 v; unsigned u[4]; };

__device__ __forceinline__ f4 mfma32(b8 a, b8 b, f4 c) {
    return __builtin_amdgcn_mfma_f32_16x16x32_bf16(a, b, c, 0, 0, 0);
}

// order-pinned loads: volatile asm so LLVM cannot sink them to their uses
__device__ __forceinline__ void gload4(f4& r, const float* p) {
    asm volatile("global_load_dwordx4 %0, %1, off" : "=v"(r) : "v"(p));
}
__device__ __forceinline__ void gload1(int& r, const int* p) {
    asm volatile("global_load_dword %0, %1, off" : "=v"(r) : "v"(p));
}

__global__ void __launch_bounds__(64) zero_out(float* o) {
    if (threadIdx.x == 0) o[0] = 0.f;
}

__global__ void __launch_bounds__(64, 1) crf_kernel(
    const float* __restrict__ em, const int* __restrict__ tags,
    const int* __restrict__ mask, const float* __restrict__ trans,
    const float* __restrict__ start_tr, const float* __restrict__ end_tr,
    float* __restrict__ out)
{
    const int lane = threadIdx.x;
    const int c    = lane & 15;     // chain within block / MFMA column
    const int g    = lane >> 4;     // 4-row group
    const int bb   = blockIdx.x * NCH;
    const int b    = bb + c;

    // ---------------- score: lane = (chain c, t-quarter g) ----------------
    float sc = 0.f;
    int   mc = 0;
    {
        int tagp = 0;
        if (g > 0) tagp = tags[(128 * g - 1) * B + b];
        #pragma unroll 4
        for (int i = 0; i < 128; ++i) {
            int t   = 128 * g + i;
            int tag = tags[t * B + b];
            int mk  = mask[t * B + b];
            mc += mk;
            if (t == 0) {
                sc += start_tr[tag] + em[(size_t)b * K + tag];
            } else {
                float add = trans[tagp * K + tag] + em[((size_t)t * B + b) * K + tag];
                sc += mk ? add : 0.f;
            }
            tagp = tag;
        }
        sc += __shfl_xor(sc, 16);  sc += __shfl_xor(sc, 32);
        mc += __shfl_xor(mc, 16);  mc += __shfl_xor(mc, 32);
        int lt = mc - 1; if (lt < 0) lt += S;
        sc += end_tr[tags[lt * B + b]];        // replicated over g
    }

    // ---------------- partition: MFMA forward algorithm ----------------
    // A[row=16tr+c][k] = exp(trans[k][16tr+c]), padded 0 for k>=48
    // operand k-map: k = 32*kc + 16*(e>>2) + 4*g + (e&3)   [verified R6: absmax 0]
    BU Afr[3][2];
    #pragma unroll
    for (int tr = 0; tr < 3; ++tr)
        #pragma unroll
        for (int kc = 0; kc < 2; ++kc)
            #pragma unroll
            for (int e = 0; e < 8; ++e) {
                int kk = 32 * kc + 16 * (e >> 2) + 4 * g + (e & 3);
                float v = (kk < K) ? __expf(trans[kk * K + 16 * tr + c]) : 0.f;
                Afr[tr][kc].v[e] = (__bf16)v;
            }

    // B init: alpha0[k] = exp(start[k] + em[0][b][k])
    BU Bf[2];
    #pragma unroll
    for (int kc = 0; kc < 2; ++kc)
        #pragma unroll
        for (int e = 0; e < 8; ++e) {
            int kk = 32 * kc + 16 * (e >> 2) + 4 * g + (e & 3);
            float v = (kk < K) ? __expf(start_tr[kk] + em[(size_t)b * K + kk]) : 1.f;
            Bf[kc].v[e] = (__bf16)v;
        }

    // prefetch ring, asm-pinned: slots i <-> t = 1+i (mod 8); 4 loads/slot
    f4  emr[PF][3];
    int mkr[PF];
    #pragma unroll
    for (int i = 0; i < PF; ++i) {
        const float* rp = em + ((size_t)(1 + i) * B + b) * K + 4 * g;
        gload4(emr[i][0], rp);
        gload4(emr[i][1], rp + 16);
        gload4(emr[i][2], rp + 32);
        gload1(mkr[i], mask + (1 + i) * B + b);
    }
    // slot0 em loads have 29 newer loads -> vmcnt(29) guarantees them (in-order)
    asm volatile("s_waitcnt vmcnt(29)" ::: "memory");
    __builtin_amdgcn_sched_barrier(0);
    f4 eem[3];
    #pragma unroll
    for (int tr = 0; tr < 3; ++tr)
        #pragma unroll
        for (int e = 0; e < 4; ++e)
            eem[tr][e] = exp2f(emr[0][tr][e] * LOG2E);

    int   offc  = 0;     // per-chain log2 offset (replicated over g)
    int   n_cur = 0;     // pending renorm for the keep-old path
    float rshfl = 0.f;   // stale-alpha renorm sample (issued early, used late)

// WAIT_: counted vmcnt in main loop; PFON_: issue next-slot loads
#define STEP(u_, WAIT_, PFON_)                                                  \
    {                                                                           \
        if ((u_) == 7) {   /* renorm sample on 1-step-stale alpha: off-chain */ \
            float rvf = (float)Bf[0].v[0];                                      \
            rshfl = __shfl(rvf, c);                                             \
        }                                                                       \
        f4 c0 = {0.f,0.f,0.f,0.f}, c1 = {0.f,0.f,0.f,0.f},                      \
           c2 = {0.f,0.f,0.f,0.f};                                              \
        c0 = mfma32(Afr[0][0].v, Bf[0].v, c0);                                  \
        c1 = mfma32(Afr[1][0].v, Bf[0].v, c1);                                  \
        c2 = mfma32(Afr[2][0].v, Bf[0].v, c2);                                  \
        c0 = mfma32(Afr[0][1].v, Bf[1].v, c0);                                  \
        c1 = mfma32(Afr[1][1].v, Bf[1].v, c1);                                  \
        c2 = mfma32(Afr[2][1].v, Bf[1].v, c2);                                  \
        c0 *= eem[0]; c1 *= eem[1]; c2 *= eem[2];                               \
        if (WAIT_) {   /* mask(t): 28 newer; em(t+1): 25 newer -> vmcnt(25) */  \
            asm volatile("s_waitcnt vmcnt(25)" ::: "memory");                   \
            __builtin_amdgcn_sched_barrier(0);                                  \
        }                                                                       \
        bool keep = mkr[u_] != 0;                                               \
        unsigned adj = (unsigned)(n_cur * 0x00800080);   /* bf16 exp-field */   \
        n_cur = 0;                                                              \
        BU nb0, nb1;                                                            \
        nb0.v[0] = (__bf16)c0[0]; nb0.v[1] = (__bf16)c0[1];                     \
        nb0.v[2] = (__bf16)c0[2]; nb0.v[3] = (__bf16)c0[3];                     \
        nb0.v[4] = (__bf16)c1[0]; nb0.v[5] = (__bf16)c1[1];                     \
        nb0.v[6] = (__bf16)c1[2]; nb0.v[7] = (__bf16)c1[3];                     \
        nb1.v[0] = (__bf16)c2[0]; nb1.v[1] = (__bf16)c2[1];                     \
        nb1.v[2] = (__bf16)c2[2]; nb1.v[3] = (__bf16)c2[3];                     \
        nb1.v[4] = nb1.v[0]; nb1.v[5] = nb1.v[1];                               \
        nb1.v[6] = nb1.v[2]; nb1.v[7] = nb1.v[3];   /* pad rows, A=0 there */   \
        _Pragma("unroll")                                                       \
        for (int w = 0; w < 4; ++w) {                                           \
            Bf[0].u[w] = keep ? nb0.u[w] : (Bf[0].u[w] - adj);                  \
            Bf[1].u[w] = keep ? nb1.u[w] : (Bf[1].u[w] - adj);                  \
        }                                                                       \
        if (PFON_) {   /* unconditional clamped loads keep vmcnt count exact */ \
            int tp = t0 + (u_) + PF;                                            \
            int tpc = tp < S - 1 ? tp : S - 1;                                  \
            const float* rp = em + ((size_t)tpc * B + b) * K + 4 * g;           \
            gload4(emr[u_][0], rp);                                             \
            gload4(emr[u_][1], rp + 16);                                        \
            gload4(emr[u_][2], rp + 32);                                        \
            gload1(mkr[u_], mask + tpc * B + b);                                \
        }                                                                       \
        float nrmf = 0.f;                                                       \
        if ((u_) == 7) {   /* finish renorm from early sample */                \
            int   E  = ((__float_as_int(rshfl) >> 23) & 255) - 127;             \
            int   n  = E + 30;             /* retarget alpha[0] to 2^-30 */     \
            offc += n;  n_cur = n;  nrmf = -(float)n;                           \
        }                                                                       \
        const int sn = ((u_) + 1) & 7;                                          \
        _Pragma("unroll")                                                       \
        for (int tr_ = 0; tr_ < 3; ++tr_)                                       \
            _Pragma("unroll")                                                   \
            for (int e_ = 0; e_ < 4; ++e_)                                      \
                eem[tr_][e_] = exp2f(fmaf(emr[sn][tr_][e_], LOG2E, nrmf));      \
    }

    // main blocks: t = 1 .. 504 (63 full blocks of 8)
    for (int t0 = 1; t0 + 7 < S; t0 += PF) {
        STEP(0,1,1) STEP(1,1,1) STEP(2,1,1) STEP(3,1,1)
        STEP(4,1,1) STEP(5,1,1) STEP(6,1,1) STEP(7,1,1)
    }
    // drain, then tail: t = 505 .. 511 (slots 0..6, fully loaded)
    asm volatile("s_waitcnt vmcnt(0)" ::: "memory");
    __builtin_amdgcn_sched_barrier(0);
    {
        const int t0 = S - 7;
        STEP(0,0,0) STEP(1,0,0) STEP(2,0,0) STEP(3,0,0)
        STEP(4,0,0) STEP(5,0,0) STEP(6,0,0)
    }
#undef STEP

    // partition_c = offc*ln2 + ln( sum_k alpha[k][c] * exp(end[k]) )
    float val = 0.f;
    #pragma unroll
    for (int e = 0; e < 4; ++e) {
        val += (float)Bf[0].v[e]     * __expf(end_tr[4 * g + e]);
        val += (float)Bf[0].v[4 + e] * __expf(end_tr[16 + 4 * g + e]);
        val += (float)Bf[1].v[e]     * __expf(end_tr[32 + 4 * g + e]);
    }
    val += __shfl_xor(val, 16);
    val += __shfl_xor(val, 32);
    float part = (float)offc * LN2 + logf(val);

    // contrib replicated 4x over g -> sum all lanes, scale by 1/4
    float contrib = part - sc;
    #pragma unroll
    for (int off = 32; off > 0; off >>= 1) contrib += __shfl_xor(contrib, off);
    if (lane == 0) atomicAdd(out, contrib * 0.25f);
}

extern "C" void kernel_launch(void* const* d_in, const int* in_sizes, int n_in,
                              void* d_out, int out_size, void* d_ws, size_t ws_size,
                              hipStream_t stream) {
    const float* em       = (const float*)d_in[0];
    const int*   tags     = (const int*)d_in[1];
    const int*   mask     = (const int*)d_in[2];
    const float* trans    = (const float*)d_in[3];
    const float* start_tr = (const float*)d_in[4];
    const float* end_tr   = (const float*)d_in[5];
    float* out = (float*)d_out;

    zero_out<<<dim3(1), dim3(64), 0, stream>>>(out);
    crf_kernel<<<dim3(NBLK), dim3(64), 0, stream>>>(em, tags, mask, trans,
                                                    start_tr, end_tr, out);
}